// Round 1
// baseline (9647.034 us; speedup 1.0000x reference)
//
#include <hip/hip_runtime.h>
#include <math.h>

#define TT 8192
#define KK 24
#define UU 104
#define NEGINF (-1e18f)

__device__ __forceinline__ float grp_max(float v) {
  v = fmaxf(v, __shfl_xor(v, 1));
  v = fmaxf(v, __shfl_xor(v, 2));
  v = fmaxf(v, __shfl_xor(v, 4));
  v = fmaxf(v, __shfl_xor(v, 8));
  v = fmaxf(v, __shfl_xor(v, 16));
  return v;
}
__device__ __forceinline__ float grp_sum(float v) {
  v += __shfl_xor(v, 1);
  v += __shfl_xor(v, 2);
  v += __shfl_xor(v, 4);
  v += __shfl_xor(v, 8);
  v += __shfl_xor(v, 16);
  return v;
}

// cum[t][k] = sum_{s<t} em[s][k]*qw[s],  t = 0..TT  (row-major [TT+1][KK])
__global__ __launch_bounds__(256) void cumsum_kernel(
    const float* __restrict__ em, const float* __restrict__ qw,
    float* __restrict__ cum)
{
  const int k = blockIdx.x;
  const int tid = threadIdx.x;
  const int lane = tid & 63;
  const int wid = tid >> 6;
  __shared__ float wsum[4];
  float carry = 0.0f;
  if (tid == 0) cum[k] = 0.0f;
  for (int c = 0; c < TT / 256; ++c) {
    int t = c * 256 + tid;
    float v = em[t * KK + k] * qw[t];
    #pragma unroll
    for (int d = 1; d < 64; d <<= 1) {
      float tmp = __shfl_up(v, d);
      if (lane >= d) v += tmp;
    }
    if (lane == 63) wsum[wid] = v;
    __syncthreads();
    float off = carry;
    #pragma unroll
    for (int w = 0; w < 4; ++w)
      if (w < wid) off += wsum[w];
    cum[(size_t)(t + 1) * KK + k] = off + v;
    carry += wsum[0] + wsum[1] + wsum[2] + wsum[3];
    __syncthreads();
  }
}

// block 0: forward scan -> alpha_out ; block 1: backward scan -> beta_out
__global__ __launch_bounds__(768, 1) void scan_kernel(
    const float* __restrict__ em,
    const float* __restrict__ log_pi,
    const float* __restrict__ log_A,
    const float* __restrict__ log_D,
    const float* __restrict__ cum,
    float* __restrict__ alpha_out,
    float* __restrict__ beta_out)
{
  __shared__ float ring[UU][25];   // phi / psi ring, row-padded -> conflict-free
  __shared__ float xbuf[2][KK];    // alpha (fwd) / m (bwd), parity double-buffered
  const int tid = threadIdx.x;
  const int g = tid >> 5;          // group = state index k (0..23)
  const int L = tid & 31;          // lane within group
  const int jl = (L < KK) ? L : 0;

  // per-lane duration weights log_D[g][u], u in {L, L+32, L+64, L+96}
  float ld0 = log_D[g * UU + L];
  float ld1 = log_D[g * UU + L + 32];
  float ld2 = log_D[g * UU + L + 64];
  float ld3 = (L < 8) ? log_D[g * UU + L + 96] : NEGINF;

  if (blockIdx.x == 0) {
    // ---------------- forward ----------------
    float Ak = (L < KK && L != g) ? log_A[L * KK + g] : NEGINF;  // A[j=L][k=g] masked
    float lpi = log_pi[g];
    float a0 = lpi + log_D[g * UU] + em[g];   // raw emission[0] per reference
    if (L == 0) {
      alpha_out[g] = a0;
      xbuf[0][g] = a0;
      ring[0][g] = lpi;                        // phi[0] = log_pi
    }
    float ccur = cum[1 * KK + g];              // cum[t] for t=1
    __syncthreads();
    int rb = 1;                                // ring slot for phi[t]
    for (int t = 1; t < TT; ++t) {
      float cnext = cum[(size_t)(t + 1) * KK + g];   // issued early, used late
      // phase 1: gamma[t-1][g] = LSE_j(alpha[t-1][j] + A[j][g]) ; phi[t]
      float v = xbuf[(t - 1) & 1][jl] + Ak;
      float mx = grp_max(v);
      float sm = grp_sum(__expf(v - mx));
      float phi = mx + __logf(sm) - ccur;
      if (L == 0) ring[rb][g] = phi;           // for future steps (u>=1 reads)
      // phase 2: alpha[t][g] = cum[t+1][g] + LSE_u(phi[t-u][g] + log_D[g][u])
      int r0 = rb - L;  if (r0 < 0) r0 += UU;
      int r1 = r0 - 32; if (r1 < 0) r1 += UU;
      int r2 = r1 - 32; if (r2 < 0) r2 += UU;
      int r3 = r2 - 32; if (r3 < 0) r3 += UU;
      float p0 = (L == 0) ? phi : ring[r0][g]; // u=0 comes from register (no intra-step dep)
      float p1 = ring[r1][g];
      float p2 = ring[r2][g];
      float p3 = ring[r3][g];
      float t0 = (L      <= t) ? p0 + ld0 : NEGINF;
      float t1 = (L + 32 <= t) ? p1 + ld1 : NEGINF;
      float t2 = (L + 64 <= t) ? p2 + ld2 : NEGINF;
      float t3 = (L + 96 <= t) ? p3 + ld3 : NEGINF;
      float mx2 = grp_max(fmaxf(fmaxf(t0, t1), fmaxf(t2, t3)));
      float s2 = grp_sum(__expf(t0 - mx2) + __expf(t1 - mx2) +
                         __expf(t2 - mx2) + __expf(t3 - mx2));
      float a = cnext + mx2 + __logf(s2);
      if (L == 0) { alpha_out[(size_t)t * KK + g] = a; xbuf[t & 1][g] = a; }
      ccur = cnext;
      rb = (rb + 1 == UU) ? 0 : rb + 1;
      __syncthreads();                          // alpha[t] handoff to next phase 1
    }
  } else {
    // ---------------- backward ----------------
    float Aj = (L < KK && L != g) ? log_A[g * KK + L] : NEGINF;  // A[j=g][k=L] masked
    float cT = cum[(size_t)TT * KK + g];
    if (L == 0) {
      beta_out[(size_t)(TT - 1) * KK + g] = 0.0f;
      ring[(TT - 1) % UU][g] = cT;             // psi[T-1] = cum[T] + 0
    }
    float psi_prev = cT;
    float c1 = cum[(size_t)(TT - 1) * KK + g]; // cum[t+1] for t = T-2
    __syncthreads();
    int rb = (TT - 1) % UU;                    // slot of psi[t+1]
    for (int t = TT - 2; t >= 0; --t) {
      float cnext = cum[(size_t)t * KK + g];   // cum[t] (= next iter's cum[t+1])
      int ulim = TT - 2 - t;
      // phase A: m[g] = -cum[t+1][g] + LSE_u(log_D[g][u] + psi[t+1+u][g])
      int s0 = rb + L;   if (s0 >= UU) s0 -= UU;
      int s1 = s0 + 32;  if (s1 >= UU) s1 -= UU;
      int s2i = s1 + 32; if (s2i >= UU) s2i -= UU;
      int s3 = s2i + 32; if (s3 >= UU) s3 -= UU;
      float q0 = (L == 0) ? psi_prev : ring[s0][g];  // u=0 register-carried
      float q1 = ring[s1][g];
      float q2 = ring[s2i][g];
      float q3 = ring[s3][g];
      float t0 = (L      <= ulim) ? q0 + ld0 : NEGINF;
      float t1 = (L + 32 <= ulim) ? q1 + ld1 : NEGINF;
      float t2 = (L + 64 <= ulim) ? q2 + ld2 : NEGINF;
      float t3 = (L + 96 <= ulim) ? q3 + ld3 : NEGINF;
      float mxa = grp_max(fmaxf(fmaxf(t0, t1), fmaxf(t2, t3)));
      float sa = grp_sum(__expf(t0 - mxa) + __expf(t1 - mxa) +
                         __expf(t2 - mxa) + __expf(t3 - mxa));
      float m = mxa + __logf(sa) - c1;
      if (L == 0) xbuf[t & 1][g] = m;
      __syncthreads();                          // m handoff (cross-group)
      // phase B: beta[t][g] = LSE_k(A[g][k] + m[k]) ; psi[t]
      float w = xbuf[t & 1][jl] + Aj;
      float mxb = grp_max(w);
      float sb = grp_sum(__expf(w - mxb));
      float bt = mxb + __logf(sb);
      float psi = c1 + bt;
      int wslot = (rb == 0) ? UU - 1 : rb - 1;  // slot t%UU
      if (L == 0) { beta_out[(size_t)t * KK + g] = bt; ring[wslot][g] = psi; }
      psi_prev = psi;
      c1 = cnext;
      rb = wslot;
      // no barrier needed: next phase A reads only own-group ring columns,
      // u=0 comes from psi_prev register, xbuf parity is disjoint
    }
  }
}

__global__ __launch_bounds__(256) void softmax_kernel(
    float* __restrict__ ab, const float* __restrict__ beta)
{
  int t = blockIdx.x * 256 + threadIdx.x;
  float s[KK];
  float mx = -INFINITY;
  #pragma unroll
  for (int k = 0; k < KK; ++k) {
    s[k] = ab[(size_t)t * KK + k] + beta[(size_t)t * KK + k];
    mx = fmaxf(mx, s[k]);
  }
  float sum = 0.0f;
  #pragma unroll
  for (int k = 0; k < KK; ++k) { s[k] = __expf(s[k] - mx); sum += s[k]; }
  float inv = 1.0f / sum;
  #pragma unroll
  for (int k = 0; k < KK; ++k) ab[(size_t)t * KK + k] = s[k] * inv;
}

extern "C" void kernel_launch(void* const* d_in, const int* in_sizes, int n_in,
                              void* d_out, int out_size, void* d_ws, size_t ws_size,
                              hipStream_t stream) {
  const float* em  = (const float*)d_in[0];   // (T,K)
  const float* qw  = (const float*)d_in[1];   // (T,)
  const float* lpi = (const float*)d_in[2];   // (K,)
  const float* lA  = (const float*)d_in[3];   // (K,K)
  const float* lD  = (const float*)d_in[4];   // (K,U)
  // d_in[5] transition_mask == 1-eye(K): applied analytically (j != k)

  float* out  = (float*)d_out;                 // alpha, then softmax in place
  float* cum  = (float*)d_ws;                  // (T+1)*K floats
  float* beta = (float*)d_ws + (size_t)(TT + 1) * KK;  // T*K floats

  cumsum_kernel<<<KK, 256, 0, stream>>>(em, qw, cum);
  scan_kernel<<<2, 768, 0, stream>>>(em, lpi, lA, lD, cum, out, beta);
  softmax_kernel<<<TT / 256, 256, 0, stream>>>(out, beta);
}

// Round 2
// 5740.923 us; speedup vs baseline: 1.6804x; 1.6804x over previous
//
#include <hip/hip_runtime.h>
#include <math.h>

#define TT 8192
#define KK 24
#define UU 104
#define NEGINF (-1e18f)
#define INV_LN2 1.4426950408889634f

__device__ __forceinline__ float exp2_(float x) {
#if __has_builtin(__builtin_amdgcn_exp2f)
  return __builtin_amdgcn_exp2f(x);
#else
  return exp2f(x);
#endif
}

template<int CTRL>
__device__ __forceinline__ float dppf(float x) {
  return __builtin_bit_cast(float,
    __builtin_amdgcn_update_dpp(0, __builtin_bit_cast(int, x), CTRL, 0xF, 0xF, true));
}
// full 16-lane-row reduction via DPP (VALU only), result broadcast to all 16 lanes
__device__ __forceinline__ float red16_max(float v) {
  v = fmaxf(v, dppf<0xB1>(v));   // quad_perm [1,0,3,2]  == xor 1
  v = fmaxf(v, dppf<0x4E>(v));   // quad_perm [2,3,0,1]  == xor 2
  v = fmaxf(v, dppf<0x124>(v));  // row_ror:4  (combines neighbor quads)
  v = fmaxf(v, dppf<0x128>(v));  // row_ror:8  (combines remaining quads)
  return v;
}
__device__ __forceinline__ float red16_sum(float v) {
  v += dppf<0xB1>(v);
  v += dppf<0x4E>(v);
  v += dppf<0x124>(v);
  v += dppf<0x128>(v);
  return v;
}

// cum[t][k] = (1/ln2) * sum_{s<t} em[s][k]*qw[s],  t = 0..TT  (row-major [TT+1][KK])
__global__ __launch_bounds__(256) void cumsum_kernel(
    const float* __restrict__ em, const float* __restrict__ qw,
    float* __restrict__ cum)
{
  const int k = blockIdx.x;
  const int tid = threadIdx.x;
  const int lane = tid & 63;
  const int wid = tid >> 6;
  __shared__ float wsum[4];
  float carry = 0.0f;
  if (tid == 0) cum[k] = 0.0f;
  for (int c = 0; c < TT / 256; ++c) {
    int t = c * 256 + tid;
    float v = em[t * KK + k] * (qw[t] * INV_LN2);
    #pragma unroll
    for (int d = 1; d < 64; d <<= 1) {
      float tmp = __shfl_up(v, d);
      if (lane >= d) v += tmp;
    }
    if (lane == 63) wsum[wid] = v;
    __syncthreads();
    float off = carry;
    #pragma unroll
    for (int w = 0; w < 4; ++w)
      if (w < wid) off += wsum[w];
    cum[(size_t)(t + 1) * KK + k] = off + v;
    carry += wsum[0] + wsum[1] + wsum[2] + wsum[3];
    __syncthreads();
  }
}

// block 0: forward scan -> alpha_out ; block 1: backward scan -> beta_out
// 24 groups x 16 lanes; all LSE reductions are DPP (no DS on critical path).
// All log-domain quantities are in log2 units.
__global__ __launch_bounds__(384, 1) void scan_kernel(
    const float* __restrict__ em,
    const float* __restrict__ log_pi,
    const float* __restrict__ log_A,
    const float* __restrict__ log_D,
    const float* __restrict__ cum,
    float* __restrict__ alpha_out,
    float* __restrict__ beta_out)
{
  __shared__ float ring[UU][25];   // phi / psi ring, pad 25 (coprime w/ 32 banks)
  __shared__ float xbuf[2][32];    // alpha (fwd) / m (bwd), parity double-buffered
  const int tid = threadIdx.x;
  const int g = tid >> 4;          // state index 0..23
  const int L = tid & 15;          // lane within 16-lane group
  const int jl2 = (L < 8) ? L + 16 : 0;

  // log_D[g][u] for u = L + 16*i  (i=0..6); u=L+96 only valid for L<8
  float ld0 = log_D[g * UU + L] * INV_LN2;
  float ld1 = log_D[g * UU + L + 16] * INV_LN2;
  float ld2 = log_D[g * UU + L + 32] * INV_LN2;
  float ld3 = log_D[g * UU + L + 48] * INV_LN2;
  float ld4 = log_D[g * UU + L + 64] * INV_LN2;
  float ld5 = log_D[g * UU + L + 80] * INV_LN2;
  float ld6 = (L < 8) ? log_D[g * UU + L + 96] * INV_LN2 : NEGINF;

  if (blockIdx.x == 0) {
    // ---------------- forward ----------------
    float Ak1 = (L != g) ? log_A[L * KK + g] * INV_LN2 : NEGINF;
    float Ak2 = (L < 8 && (L + 16) != g) ? log_A[(L + 16) * KK + g] * INV_LN2 : NEGINF;
    float lpi2 = log_pi[g] * INV_LN2;
    float a0 = lpi2 + log_D[g * UU] * INV_LN2 + em[g] * INV_LN2;
    if (L == 0) {
      alpha_out[g] = a0;
      xbuf[0][g] = a0;
      ring[0][g] = lpi2;           // phi[0] = log_pi
    }
    // depth-3 register pipeline over the cum stream (hides cold-miss latency)
    float ccur = cum[1 * KK + g];
    float c1 = cum[2 * KK + g];
    float c2 = cum[3 * KK + g];
    float c3 = cum[4 * KK + g];
    int rb = 1;
    __syncthreads();

    auto fstep = [&](int t, bool MASKED) {
      int tpre = t + 4; if (tpre > TT) tpre = TT;
      float c4 = cum[(size_t)tpre * KK + g];
      // early ring reads (previous steps' phi); lane0's p0 replaced by register
      int r = rb - L; if (r < 0) r += UU;
      float p0 = ring[r][g];
      r -= 16; if (r < 0) r += UU; float p1 = ring[r][g];
      r -= 16; if (r < 0) r += UU; float p2 = ring[r][g];
      r -= 16; if (r < 0) r += UU; float p3 = ring[r][g];
      r -= 16; if (r < 0) r += UU; float p4 = ring[r][g];
      r -= 16; if (r < 0) r += UU; float p5 = ring[r][g];
      r -= 16; if (r < 0) r += UU; float p6 = ring[r][g];
      // phase 1: phi[t] = LSE_j(alpha[t-1][j] + A[j][g]) - cum[t]
      const float* xb = xbuf[(t - 1) & 1];
      float v1 = xb[L] + Ak1;
      float v2 = xb[jl2] + Ak2;
      float mx = red16_max(fmaxf(v1, v2));
      float sm = red16_sum(exp2_(v1 - mx) + exp2_(v2 - mx));
      float phi = mx + __log2f(sm) - ccur;
      if (L == 0) ring[rb][g] = phi;
      // phase 2: alpha[t] = cum[t+1] + LSE_u(phi[t-u] + log_D[g][u])
      float u0 = (L == 0) ? phi + ld0 : ((MASKED && L > t) ? NEGINF : p0 + ld0);
      float u1 = (MASKED && L + 16 > t) ? NEGINF : p1 + ld1;
      float u2 = (MASKED && L + 32 > t) ? NEGINF : p2 + ld2;
      float u3 = (MASKED && L + 48 > t) ? NEGINF : p3 + ld3;
      float u4 = (MASKED && L + 64 > t) ? NEGINF : p4 + ld4;
      float u5 = (MASKED && L + 80 > t) ? NEGINF : p5 + ld5;
      float u6 = (MASKED && L + 96 > t) ? NEGINF : p6 + ld6;
      float m2 = red16_max(fmaxf(fmaxf(fmaxf(u0, u1), fmaxf(u2, u3)),
                                 fmaxf(fmaxf(u4, u5), u6)));
      float s2 = red16_sum(((exp2_(u0 - m2) + exp2_(u1 - m2)) +
                            (exp2_(u2 - m2) + exp2_(u3 - m2))) +
                           ((exp2_(u4 - m2) + exp2_(u5 - m2)) + exp2_(u6 - m2)));
      float a = c1 + m2 + __log2f(s2);
      if (L == 0) { alpha_out[(size_t)t * KK + g] = a; xbuf[t & 1][g] = a; }
      ccur = c1; c1 = c2; c2 = c3; c3 = c4;
      rb = (rb + 1 == UU) ? 0 : rb + 1;
      __syncthreads();
    };
    for (int t = 1; t < UU; ++t) fstep(t, true);
    for (int t = UU; t < TT; ++t) fstep(t, false);
  } else {
    // ---------------- backward ----------------
    float Aj1 = (L != g) ? log_A[g * KK + L] * INV_LN2 : NEGINF;
    float Aj2 = (L < 8 && (L + 16) != g) ? log_A[g * KK + L + 16] * INV_LN2 : NEGINF;
    float cT = cum[(size_t)TT * KK + g];
    if (L == 0) {
      beta_out[(size_t)(TT - 1) * KK + g] = 0.0f;
      ring[(TT - 1) % UU][g] = cT;             // psi[T-1] = cum[T] + 0
    }
    float psi_prev = cT;
    float c1 = cum[(size_t)(TT - 1) * KK + g]; // cum[t+1] for t = TT-2
    float d1 = cum[(size_t)(TT - 2) * KK + g];
    float d2 = cum[(size_t)(TT - 3) * KK + g];
    int rb = (TT - 1) % UU;                    // slot of psi[t+1]
    __syncthreads();

    auto bstep = [&](int t, bool MASKED) {
      int tpre = t - 2; if (tpre < 0) tpre = 0;
      float d3 = cum[(size_t)tpre * KK + g];
      // early psi ring reads; lane0's q0 replaced by register
      int s = rb + L; if (s >= UU) s -= UU;
      float q0 = ring[s][g];
      s += 16; if (s >= UU) s -= UU; float q1 = ring[s][g];
      s += 16; if (s >= UU) s -= UU; float q2 = ring[s][g];
      s += 16; if (s >= UU) s -= UU; float q3 = ring[s][g];
      s += 16; if (s >= UU) s -= UU; float q4 = ring[s][g];
      s += 16; if (s >= UU) s -= UU; float q5 = ring[s][g];
      s += 16; if (s >= UU) s -= UU; float q6 = ring[s][g];
      int ulim = TT - 2 - t;
      // phase A: m[g] = LSE_u(log_D[g][u] + psi[t+1+u][g]) - cum[t+1]
      float u0 = (L == 0) ? psi_prev + ld0 : ((MASKED && L > ulim) ? NEGINF : q0 + ld0);
      float u1 = (MASKED && L + 16 > ulim) ? NEGINF : q1 + ld1;
      float u2 = (MASKED && L + 32 > ulim) ? NEGINF : q2 + ld2;
      float u3 = (MASKED && L + 48 > ulim) ? NEGINF : q3 + ld3;
      float u4 = (MASKED && L + 64 > ulim) ? NEGINF : q4 + ld4;
      float u5 = (MASKED && L + 80 > ulim) ? NEGINF : q5 + ld5;
      float u6 = (MASKED && L + 96 > ulim) ? NEGINF : q6 + ld6;
      float mxa = red16_max(fmaxf(fmaxf(fmaxf(u0, u1), fmaxf(u2, u3)),
                                  fmaxf(fmaxf(u4, u5), u6)));
      float sa = red16_sum(((exp2_(u0 - mxa) + exp2_(u1 - mxa)) +
                            (exp2_(u2 - mxa) + exp2_(u3 - mxa))) +
                           ((exp2_(u4 - mxa) + exp2_(u5 - mxa)) + exp2_(u6 - mxa)));
      float m = mxa + __log2f(sa) - c1;
      if (L == 0) xbuf[t & 1][g] = m;
      __syncthreads();                          // m handoff (cross-group)
      // phase B: beta[t][g] = LSE_k(A[g][k] + m[k]) ; psi[t] = cum[t+1] + beta[t]
      const float* xb = xbuf[t & 1];
      float w1 = xb[L] + Aj1;
      float w2 = xb[jl2] + Aj2;
      float mxb = red16_max(fmaxf(w1, w2));
      float sb = red16_sum(exp2_(w1 - mxb) + exp2_(w2 - mxb));
      float bt = mxb + __log2f(sb);
      float psi = c1 + bt;
      int wslot = (rb == 0) ? UU - 1 : rb - 1;  // slot t%UU
      if (L == 0) { beta_out[(size_t)t * KK + g] = bt; ring[wslot][g] = psi; }
      psi_prev = psi;
      c1 = d1; d1 = d2; d2 = d3;
      rb = wslot;
      // no end barrier: next phase A reads only own-group ring columns (same wave),
      // u=0 via psi_prev register, xbuf parity disjoint
    };
    for (int t = TT - 2; t > TT - 2 - 103; --t) bstep(t, true);   // ulim 0..102
    for (int t = TT - 2 - 103; t >= 0; --t) bstep(t, false);      // ulim >= 103
  }
}

// out = softmax over k of (alpha2 + beta2), both in log2 domain (ratios identical)
__global__ __launch_bounds__(256) void softmax_kernel(
    float* __restrict__ ab, const float* __restrict__ beta)
{
  int t = blockIdx.x * 256 + threadIdx.x;
  float s[KK];
  float mx = -INFINITY;
  #pragma unroll
  for (int k = 0; k < KK; ++k) {
    s[k] = ab[(size_t)t * KK + k] + beta[(size_t)t * KK + k];
    mx = fmaxf(mx, s[k]);
  }
  float sum = 0.0f;
  #pragma unroll
  for (int k = 0; k < KK; ++k) { s[k] = exp2_(s[k] - mx); sum += s[k]; }
  float inv = 1.0f / sum;
  #pragma unroll
  for (int k = 0; k < KK; ++k) ab[(size_t)t * KK + k] = s[k] * inv;
}

extern "C" void kernel_launch(void* const* d_in, const int* in_sizes, int n_in,
                              void* d_out, int out_size, void* d_ws, size_t ws_size,
                              hipStream_t stream) {
  const float* em  = (const float*)d_in[0];   // (T,K)
  const float* qw  = (const float*)d_in[1];   // (T,)
  const float* lpi = (const float*)d_in[2];   // (K,)
  const float* lA  = (const float*)d_in[3];   // (K,K)
  const float* lD  = (const float*)d_in[4];   // (K,U)
  // d_in[5] transition_mask == 1-eye(K): applied analytically (j != k)

  float* out  = (float*)d_out;                 // alpha2, then softmax in place
  float* cum  = (float*)d_ws;                  // (T+1)*K floats
  float* beta = (float*)d_ws + (size_t)(TT + 1) * KK;  // T*K floats

  cumsum_kernel<<<KK, 256, 0, stream>>>(em, qw, cum);
  scan_kernel<<<2, 384, 0, stream>>>(em, lpi, lA, lD, cum, out, beta);
  softmax_kernel<<<TT / 256, 256, 0, stream>>>(out, beta);
}

// Round 3
// 3740.391 us; speedup vs baseline: 2.5792x; 1.5348x over previous
//
#include <hip/hip_runtime.h>
#include <math.h>

#define TT 8192
#define KK 24
#define UU 104
#define NEGINF (-1e18f)
#define INV_LN2 1.4426950408889634f

__device__ __forceinline__ float exp2_(float x) {
#if __has_builtin(__builtin_amdgcn_exp2f)
  return __builtin_amdgcn_exp2f(x);
#else
  return exp2f(x);
#endif
}

template<int CTRL>
__device__ __forceinline__ float dppf(float x) {
  return __builtin_bit_cast(float,
    __builtin_amdgcn_update_dpp(0, __builtin_bit_cast(int, x), CTRL, 0xF, 0xF, true));
}
// 16-lane-row sum reduction via DPP, result broadcast to all 16 lanes
__device__ __forceinline__ float red16_sum(float v) {
  v += dppf<0xB1>(v);   // quad_perm xor1
  v += dppf<0x4E>(v);   // quad_perm xor2
  v += dppf<0x124>(v);  // row_ror:4
  v += dppf<0x128>(v);  // row_ror:8
  return v;
}
// dst[L] = src[(L-1)&15]  (row_ror:1)
__device__ __forceinline__ float ror1(float x) { return dppf<0x121>(x); }

// cum[t][k] = (1/ln2) * sum_{s<t} em[s][k]*qw[s],  t = 0..TT  (row-major [TT+1][KK])
__global__ __launch_bounds__(256) void cumsum_kernel(
    const float* __restrict__ em, const float* __restrict__ qw,
    float* __restrict__ cum)
{
  const int k = blockIdx.x;
  const int tid = threadIdx.x;
  const int lane = tid & 63;
  const int wid = tid >> 6;
  __shared__ float wsum[4];
  float carry = 0.0f;
  if (tid == 0) cum[k] = 0.0f;
  for (int c = 0; c < TT / 256; ++c) {
    int t = c * 256 + tid;
    float v = em[t * KK + k] * (qw[t] * INV_LN2);
    #pragma unroll
    for (int d = 1; d < 64; d <<= 1) {
      float tmp = __shfl_up(v, d);
      if (lane >= d) v += tmp;
    }
    if (lane == 63) wsum[wid] = v;
    __syncthreads();
    float off = carry;
    #pragma unroll
    for (int w = 0; w < 4; ++w)
      if (w < wid) off += wsum[w];
    cum[(size_t)(t + 1) * KK + k] = off + v;
    carry += wsum[0] + wsum[1] + wsum[2] + wsum[3];
    __syncthreads();
  }
}

// block 0: forward -> alpha_out ; block 1: backward -> beta_out
// 24 groups x 16 lanes. phi/psi window lives in registers, shifted cross-lane
// by row_ror:1 each step. All LSEs anchored on previous-step values (no max pass).
// All log quantities in log2 units.
__global__ __launch_bounds__(384, 1) void scan_kernel(
    const float* __restrict__ em,
    const float* __restrict__ log_pi,
    const float* __restrict__ log_A,
    const float* __restrict__ log_D,
    const float* __restrict__ cum,
    float* __restrict__ alpha_out,
    float* __restrict__ beta_out)
{
  __shared__ __align__(16) float xbuf[2][32];  // alpha (fwd) / m (bwd), parity dbuf
  const int tid = threadIdx.x;
  const int g = tid >> 4;          // state 0..23
  const int L = tid & 15;          // lane in group
  const bool l0 = (L == 0);
  const int j1 = 2 * L, j2 = 2 * L + 1;

  if (tid < 8) { xbuf[0][24 + tid] = 0.0f; xbuf[1][24 + tid] = 0.0f; }

  // log_D[g][u], u = L + 16*i
  float ld0 = log_D[g * UU + L] * INV_LN2;
  float ld1 = log_D[g * UU + L + 16] * INV_LN2;
  float ld2 = log_D[g * UU + L + 32] * INV_LN2;
  float ld3 = log_D[g * UU + L + 48] * INV_LN2;
  float ld4 = log_D[g * UU + L + 64] * INV_LN2;
  float ld5 = log_D[g * UU + L + 80] * INV_LN2;
  float ld6 = (L < 8) ? log_D[g * UU + L + 96] * INV_LN2 : NEGINF;

  if (blockIdx.x == 0) {
    // ---------------- forward ----------------
    float Ak1 = (j1 < KK && j1 != g) ? log_A[j1 * KK + g] * INV_LN2 : NEGINF;
    float Ak2 = (j2 < KK && j2 != g) ? log_A[j2 * KK + g] * INV_LN2 : NEGINF;
    float lpi2 = log_pi[g] * INV_LN2;
    float a0 = lpi2 + log_D[g * UU] * INV_LN2 + em[g] * INV_LN2;
    if (l0) { alpha_out[g] = a0; xbuf[0][g] = a0; }
    // P_i[L] = phi[t-1 - (L+16i)] state entering step t (t=1: only phi[0]=log_pi)
    float P0 = l0 ? lpi2 : NEGINF;
    float P1 = NEGINF, P2 = NEGINF, P3 = NEGINF,
          P4 = NEGINF, P5 = NEGINF, P6 = NEGINF;
    float ccur = cum[1 * KK + g], c1 = cum[2 * KK + g],
          c2 = cum[3 * KK + g],  c3 = cum[4 * KK + g];
    float Mh = a0;          // anchor for gamma LSE
    float Ua = a0 - ccur;   // anchor for u-window LSE (alpha - cum)
    __syncthreads();
    for (int t = 1; t < TT; ++t) {
      int tp = t + 4; if (tp > TT) tp = TT;
      float c4 = cum[(size_t)tp * KK + g];
      // shift phi window by one step (register ring via DPP row rotate)
      float r0 = ror1(P0), r1 = ror1(P1), r2 = ror1(P2), r3 = ror1(P3),
            r4 = ror1(P4), r5 = ror1(P5), r6 = ror1(P6);
      P1 = l0 ? r0 : r1;  P2 = l0 ? r1 : r2;  P3 = l0 ? r2 : r3;
      P4 = l0 ? r3 : r4;  P5 = l0 ? r4 : r5;  P6 = l0 ? r5 : r6;
      // phase-2 partials independent of phi[t] (precompute off critical path)
      float e1 = exp2_(P1 + (ld1 - Ua));
      float e2 = exp2_(P2 + (ld2 - Ua));
      float e3 = exp2_(P3 + (ld3 - Ua));
      float e4 = exp2_(P4 + (ld4 - Ua));
      float e5 = exp2_(P5 + (ld5 - Ua));
      float e6 = exp2_(P6 + (ld6 - Ua));
      float e0nz = exp2_(r0 + (ld0 - Ua));
      float srest = ((e1 + e2) + (e3 + e4)) + (e5 + e6);
      // phase 1: gamma[t][g] = Mh + log2( sum_j 2^(alpha[t-1][j]+A[j][g]-Mh) )
      float2 av = *(const float2*)&xbuf[(t - 1) & 1][j1];
      float w1 = av.x + (Ak1 - Mh);
      float w2 = av.y + (Ak2 - Mh);
      float s1 = red16_sum(exp2_(w1) + exp2_(w2));
      float gamma = Mh + __log2f(s1);
      Mh = gamma;
      float phi = gamma - ccur;
      P0 = l0 ? phi : r0;
      // phase 2: alpha[t] = cum[t+1] + Ua + log2( sum_u 2^(phi[t-u]+ld[u]-Ua) )
      float e0 = l0 ? exp2_(phi + (ld0 - Ua)) : e0nz;
      float S = red16_sum(e0 + srest);
      float ua = Ua + __log2f(S);
      float a = c1 + ua;
      Ua = ua;
      if (l0) { xbuf[t & 1][g] = a; alpha_out[(size_t)t * KK + g] = a; }
      ccur = c1; c1 = c2; c2 = c3; c3 = c4;
      __syncthreads();
    }
  } else {
    // ---------------- backward ----------------
    float Bj1 = (j1 < KK && j1 != g) ? log_A[g * KK + j1] * INV_LN2 : NEGINF;
    float Bj2 = (j2 < KK && j2 != g) ? log_A[g * KK + j2] * INV_LN2 : NEGINF;
    float cT = cum[(size_t)TT * KK + g];
    if (l0) beta_out[(size_t)(TT - 1) * KK + g] = 0.0f;
    // Q_i[L] = psi[t+1 + L+16i] for step t; init for t=TT-2 (only psi[TT-1]=cum[TT])
    float Q0 = l0 ? cT : NEGINF;
    float Q1 = NEGINF, Q2 = NEGINF, Q3 = NEGINF,
          Q4 = NEGINF, Q5 = NEGINF, Q6 = NEGINF;
    float c1 = cum[(size_t)(TT - 1) * KK + g];
    float d1 = cum[(size_t)(TT - 2) * KK + g];
    float d2 = cum[(size_t)(TT - 3) * KK + g];
    float nh = cT;    // anchor for n = m + cum[t+1]
    float bh = 0.0f;  // anchor for beta
    __syncthreads();
    for (int t = TT - 2; t >= 0; --t) {
      int tp = t - 2; if (tp < 0) tp = 0;
      float d3 = cum[(size_t)tp * KK + g];
      // phase A: n = nh + log2( sum_u 2^(ld[u]+psi[t+1+u]-nh) );  m = n - cum[t+1]
      float x0 = exp2_(Q0 + (ld0 - nh));
      float x1 = exp2_(Q1 + (ld1 - nh));
      float x2 = exp2_(Q2 + (ld2 - nh));
      float x3 = exp2_(Q3 + (ld3 - nh));
      float x4 = exp2_(Q4 + (ld4 - nh));
      float x5 = exp2_(Q5 + (ld5 - nh));
      float x6 = exp2_(Q6 + (ld6 - nh));
      float sA = red16_sum(((x0 + x1) + (x2 + x3)) + ((x4 + x5) + x6));
      float n = nh + __log2f(sA);
      nh = n;
      float m = n - c1;
      if (l0) xbuf[t & 1][g] = m;
      __syncthreads();
      // phase B: beta[t][g] = bh + log2( sum_k 2^(A[g][k]+m[k]-bh) )
      float2 mv = *(const float2*)&xbuf[t & 1][j1];
      float y1 = mv.x + (Bj1 - bh);
      float y2 = mv.y + (Bj2 - bh);
      float sB = red16_sum(exp2_(y1) + exp2_(y2));
      float bt = bh + __log2f(sB);
      bh = bt;
      float psi = c1 + bt;
      if (l0) beta_out[(size_t)t * KK + g] = bt;
      // shift psi window for step t-1: new entry psi[t] at lane 0 of Q0
      float q0 = ror1(Q0), q1 = ror1(Q1), q2 = ror1(Q2), q3 = ror1(Q3),
            q4 = ror1(Q4), q5 = ror1(Q5), q6 = ror1(Q6);
      Q6 = l0 ? q5 : q6;  Q5 = l0 ? q4 : q5;  Q4 = l0 ? q3 : q4;
      Q3 = l0 ? q2 : q3;  Q2 = l0 ? q1 : q2;  Q1 = l0 ? q0 : q1;
      Q0 = l0 ? psi : q0;
      c1 = d1; d1 = d2; d2 = d3;
    }
  }
}

// out = softmax over k of (alpha2 + beta2), log2 domain (ratios identical)
__global__ __launch_bounds__(256) void softmax_kernel(
    float* __restrict__ ab, const float* __restrict__ beta)
{
  int t = blockIdx.x * 256 + threadIdx.x;
  float s[KK];
  float mx = -INFINITY;
  #pragma unroll
  for (int k = 0; k < KK; ++k) {
    s[k] = ab[(size_t)t * KK + k] + beta[(size_t)t * KK + k];
    mx = fmaxf(mx, s[k]);
  }
  float sum = 0.0f;
  #pragma unroll
  for (int k = 0; k < KK; ++k) { s[k] = exp2_(s[k] - mx); sum += s[k]; }
  float inv = 1.0f / sum;
  #pragma unroll
  for (int k = 0; k < KK; ++k) ab[(size_t)t * KK + k] = s[k] * inv;
}

extern "C" void kernel_launch(void* const* d_in, const int* in_sizes, int n_in,
                              void* d_out, int out_size, void* d_ws, size_t ws_size,
                              hipStream_t stream) {
  const float* em  = (const float*)d_in[0];   // (T,K)
  const float* qw  = (const float*)d_in[1];   // (T,)
  const float* lpi = (const float*)d_in[2];   // (K,)
  const float* lA  = (const float*)d_in[3];   // (K,K)
  const float* lD  = (const float*)d_in[4];   // (K,U)
  // d_in[5] transition_mask == 1-eye(K): applied analytically (j != k)

  float* out  = (float*)d_out;                 // alpha2, then softmax in place
  float* cum  = (float*)d_ws;                  // (T+1)*K floats
  float* beta = (float*)d_ws + (size_t)(TT + 1) * KK;  // T*K floats

  cumsum_kernel<<<KK, 256, 0, stream>>>(em, qw, cum);
  scan_kernel<<<2, 384, 0, stream>>>(em, lpi, lA, lD, cum, out, beta);
  softmax_kernel<<<TT / 256, 256, 0, stream>>>(out, beta);
}